// Round 14
// baseline (185.432 us; speedup 1.0000x reference)
//
#include <hip/hip_runtime.h>

// PointNet 3-NN feature interpolation, v14: x-sorted band pruning.
// bins_count : histogram points & queries into 256 x-bins (per batch).
// bins_scan  : exclusive scan -> base/cursor for both.
// knn3_tau   : v9-proven; tau sub-partials over pts 0..1023 (orig order).
// tau3_merge : tau[q] = 3rd-smallest over first 1024 pts.
// scatter    : counting-sort points ({2x,2y,2z,norm}+idx) and queries
//              (x,y,z,qss,tau,qid) by x-bin.
// knn3_band  : block = 256 sorted queries x segment; scans only the sorted
//              point range within [qxmin-r, qxmax+r], r^2 = taumax+margin.
//              Exact: outside band => computed d > tau >= d2_final.
// knn3_bmerge: lex-merge 16 segment partials, weights, scatter by qid.
// interp     : per-(b,d) row staged in LDS, gather+weighted-sum.

constexpr int   QT    = 256;
constexpr int   NB    = 256;       // x bins
constexpr float GORG  = -4.0f;
constexpr float GIW   = 32.0f;     // 1/binwidth, binwidth = 0.03125 (pow2)
constexpr int   SCS   = 64;        // tau sub-chunk points
constexpr int   NSUB  = 16;        // tau sub-chunks (1024 pts)
constexpr int   NSEG  = 16;        // band segments (partial slots)
constexpr float DINF  = 3.4e38f;
constexpr int   ISENT = 0x7fffffff;

__device__ __forceinline__ int binOf(float x) {
    int c = (int)floorf((x - GORG) * GIW);
    return min(NB - 1, max(0, c));
}

// guarded lexicographic (d, idx) insert — order-independent top-3
__device__ __forceinline__ void ins_lex(float& d0, float& d1, float& d2,
                                        int& i0, int& i1, int& i2,
                                        float d, int n) {
    bool l2 = (d < d2) || (d == d2 && n < i2);
    if (l2) {
        bool l1 = (d < d1) || (d == d1 && n < i1);
        bool l0 = (d < d0) || (d == d0 && n < i0);
        d2 = l1 ? d1 : d;  i2 = l1 ? i1 : n;
        d1 = l0 ? d0 : (l1 ? d : d1);
        i1 = l0 ? i0 : (l1 ? n : i1);
        d0 = l0 ? d  : d0; i0 = l0 ? n : i0;
    }
}

__device__ __forceinline__ void ins_lex_nb(float& d0, float& d1, float& d2,
                                           int& i0, int& i1, int& i2,
                                           float d, int n) {
    bool l2 = (d < d2) || (d == d2 && n < i2);
    bool l1 = (d < d1) || (d == d1 && n < i1);
    bool l0 = (d < d0) || (d == d0 && n < i0);
    float nd2 = l1 ? d1 : (l2 ? d : d2);
    int   ni2 = l1 ? i1 : (l2 ? n : i2);
    float nd1 = l0 ? d0 : (l1 ? d : d1);
    int   ni1 = l0 ? i0 : (l1 ? n : i1);
    d0 = l0 ? d : d0;  i0 = l0 ? n : i0;
    d1 = nd1; d2 = nd2; i1 = ni1; i2 = ni2;
}

// value-only top-3 insert
__device__ __forceinline__ void ins_v(float& d0, float& d1, float& d2, float d) {
    bool c0 = d < d0, c1 = d < d1, c2 = d < d2;
    float n2 = c1 ? d1 : (c2 ? d : d2);
    float n1 = c0 ? d0 : (c1 ? d : d1);
    d0 = c0 ? d : d0; d1 = n1; d2 = n2;
}

__global__ __launch_bounds__(256)
void bins_count(const float* __restrict__ xyz1, const float* __restrict__ xyz2,
                int B, int N, int S,
                int* __restrict__ pcnt, int* __restrict__ qcnt)
{
    int t = blockIdx.x * 256 + threadIdx.x;
    int BN = B * N;
    if (t < BN) {
        int b = t / N, n = t - b * N;
        float x = xyz1[(size_t)b * 3 * N + n];
        atomicAdd(&pcnt[b * NB + binOf(x)], 1);
    } else if (t < BN + B * S) {
        int i = t - BN;
        int b = i / S, s = i - b * S;
        float x = xyz2[(size_t)b * 3 * S + s];
        atomicAdd(&qcnt[b * NB + binOf(x)], 1);
    }
}

__global__ __launch_bounds__(256)
void bins_scan(const int* __restrict__ pcnt, const int* __restrict__ qcnt,
               int* __restrict__ pbase, int* __restrict__ pcur,
               int* __restrict__ qbase, int* __restrict__ qcur)
{
    __shared__ int sm[NB];
    const int b = blockIdx.x, tid = threadIdx.x;
    // points
    sm[tid] = pcnt[b * NB + tid];
    __syncthreads();
    for (int o = 1; o < NB; o <<= 1) {
        int v = (tid >= o) ? sm[tid - o] : 0;
        __syncthreads(); sm[tid] += v; __syncthreads();
    }
    int excl = tid ? sm[tid - 1] : 0;
    pbase[b * NB + tid] = excl; pcur[b * NB + tid] = excl;
    __syncthreads();
    // queries
    sm[tid] = qcnt[b * NB + tid];
    __syncthreads();
    for (int o = 1; o < NB; o <<= 1) {
        int v = (tid >= o) ? sm[tid - o] : 0;
        __syncthreads(); sm[tid] += v; __syncthreads();
    }
    excl = tid ? sm[tid - 1] : 0;
    qbase[b * NB + tid] = excl; qcur[b * NB + tid] = excl;
}

// ---- tau pipeline (v9-proven, reads xyz1 in ORIGINAL order) ----
__device__ __forceinline__ void stage_chunk64(float4* spt,
                                              const float* __restrict__ bx,
                                              int N, int tid) {
#pragma clang fp contract(off)
    const float* __restrict__ by = bx + N;
    const float* __restrict__ bz = by + N;
    for (int i = tid * 4; i < SCS; i += QT * 4) {
        float4 vx = *reinterpret_cast<const float4*>(bx + i);
        float4 vy = *reinterpret_cast<const float4*>(by + i);
        float4 vz = *reinterpret_cast<const float4*>(bz + i);
        spt[i + 0] = make_float4(vx.x + vx.x, vy.x + vy.x, vz.x + vz.x,
                                 (vx.x*vx.x + vy.x*vy.x) + vz.x*vz.x);
        spt[i + 1] = make_float4(vx.y + vx.y, vy.y + vy.y, vz.y + vz.y,
                                 (vx.y*vx.y + vy.y*vy.y) + vz.y*vz.y);
        spt[i + 2] = make_float4(vx.z + vx.z, vy.z + vy.z, vz.z + vz.z,
                                 (vx.z*vx.z + vy.z*vy.z) + vz.z*vz.z);
        spt[i + 3] = make_float4(vx.w + vx.w, vy.w + vy.w, vz.w + vz.w,
                                 (vx.w*vx.w + vy.w*vy.w) + vz.w*vz.w);
    }
}

__global__ __launch_bounds__(256)
void knn3_tau(const float* __restrict__ xyz1, const float* __restrict__ xyz2,
              int B, int N, int S, int BS,
              float* __restrict__ sd0, float* __restrict__ sd1,
              float* __restrict__ sd2)
{
#pragma clang fp contract(off)
    __shared__ float4 spt[SCS];
    const int tid = threadIdx.x;
    const int q   = blockIdx.x * QT + tid;
    const int c   = blockIdx.y;
    const int b   = q / S;
    const int s   = q - b * S;

    stage_chunk64(spt, xyz1 + (size_t)b * 3 * N + c * SCS, N, tid);
    __syncthreads();

    const float* __restrict__ q2p = xyz2 + (size_t)b * 3 * S;
    const float qx = q2p[s];
    const float qy = q2p[S + s];
    const float qz = q2p[2 * S + s];
    const float qss = (qx * qx + qy * qy) + qz * qz;

    float d0 = DINF, d1 = DINF, d2 = DINF;
#pragma unroll 8
    for (int k = 0; k < SCS; ++k) {
        float4 p = spt[k];
        float dot2 = (qx * p.x + qy * p.y) + qz * p.z;   // == 2*dot, exact
        float d    = (qss + p.w) - dot2;
        ins_v(d0, d1, d2, d);
    }
    const size_t off = (size_t)c * BS + q;
    sd0[off] = d0; sd1[off] = d1; sd2[off] = d2;
}

__global__ __launch_bounds__(256)
void tau3_merge(const float* __restrict__ sd0, const float* __restrict__ sd1,
                const float* __restrict__ sd2, int BS,
                float* __restrict__ tau)
{
    const int q = blockIdx.x * 256 + threadIdx.x;
    if (q >= BS) return;
    float d0 = DINF, d1 = DINF, d2 = DINF;
#pragma unroll
    for (int c = 0; c < NSUB; ++c) {
        const size_t off = (size_t)c * BS + q;
        ins_v(d0, d1, d2, sd0[off]);
        ins_v(d0, d1, d2, sd1[off]);
        ins_v(d0, d1, d2, sd2[off]);
    }
    tau[q] = d2;
}

// ---- counting-sort scatter: points (packed) and queries (+tau, qid) ----
__global__ __launch_bounds__(256)
void scatter_all(const float* __restrict__ xyz1, const float* __restrict__ xyz2,
                 const float* __restrict__ tau,
                 int* __restrict__ pcur, int* __restrict__ qcur,
                 float4* __restrict__ spk, int* __restrict__ ssidx,
                 float* __restrict__ sqx, float* __restrict__ sqy,
                 float* __restrict__ sqz, float* __restrict__ sqs,
                 float* __restrict__ stau, int* __restrict__ sqid,
                 int B, int N, int S)
{
#pragma clang fp contract(off)
    int t = blockIdx.x * 256 + threadIdx.x;
    int BN = B * N;
    if (t < BN) {
        int b = t / N, n = t - b * N;
        const float* __restrict__ bx = xyz1 + (size_t)b * 3 * N;
        float x = bx[n], y = bx[N + n], z = bx[2 * N + n];
        int slot = atomicAdd(&pcur[b * NB + binOf(x)], 1);
        // {2x,2y,2z,norm}: pow2-exact doubling; norm in np sum order
        spk[(size_t)b * N + slot]  = make_float4(x + x, y + y, z + z,
                                                 (x * x + y * y) + z * z);
        ssidx[(size_t)b * N + slot] = n;
    } else if (t < BN + B * S) {
        int i = t - BN;
        int b = i / S, s = i - b * S;
        const float* __restrict__ qp = xyz2 + (size_t)b * 3 * S;
        float x = qp[s], y = qp[S + s], z = qp[2 * S + s];
        int slot = atomicAdd(&qcur[b * NB + binOf(x)], 1);
        int pos = b * S + slot;
        sqx[pos] = x; sqy[pos] = y; sqz[pos] = z;
        sqs[pos] = (x * x + y * y) + z * z;       // np sum order
        stau[pos] = tau[b * S + s];
        sqid[pos] = b * S + s;
    }
}

// ---- band scan ----
__global__ __launch_bounds__(256)
void knn3_band(const float4* __restrict__ spk, const int* __restrict__ ssidx,
               const float* __restrict__ sqx, const float* __restrict__ sqy,
               const float* __restrict__ sqz, const float* __restrict__ sqs,
               const float* __restrict__ stau,
               const int* __restrict__ pbase, const int* __restrict__ pcnt,
               int B, int N, int S, int BS,
               float* __restrict__ pd0, float* __restrict__ pd1,
               float* __restrict__ pd2,
               int* __restrict__ pi0, int* __restrict__ pi1,
               int* __restrict__ pi2)
{
#pragma clang fp contract(off)
    __shared__ float4 s_p[256];
    __shared__ int    s_i[256];
    __shared__ float  red[256];
    const int tid = threadIdx.x;
    const int t   = blockIdx.x;               // query tile (256 sorted q)
    const int g   = blockIdx.y;               // segment
    const int gq  = t * 256 + tid;
    const int b   = t / (S / 256);

    const float qx = sqx[gq], qy = sqy[gq], qz = sqz[gq];
    const float qs_ = sqs[gq];
    const float tq  = stau[gq];

    // block reductions: taumax, qxmin, qxmax
    red[tid] = tq; __syncthreads();
    for (int o = 128; o >= 1; o >>= 1) {
        if (tid < o) red[tid] = fmaxf(red[tid], red[tid + o]);
        __syncthreads();
    }
    const float tmax = red[0]; __syncthreads();
    red[tid] = qx; __syncthreads();
    for (int o = 128; o >= 1; o >>= 1) {
        if (tid < o) red[tid] = fminf(red[tid], red[tid + o]);
        __syncthreads();
    }
    const float qmn = red[0]; __syncthreads();
    red[tid] = qx; __syncthreads();
    for (int o = 128; o >= 1; o >>= 1) {
        if (tid < o) red[tid] = fmaxf(red[tid], red[tid + o]);
        __syncthreads();
    }
    const float qmx = red[0]; __syncthreads();

    // band: |px - qx| > r  =>  computed d > tmax >= tau(q)  (margin 1e-3
    // dominates the ~1e-5 abs rounding error of the distance formula)
    const float r = sqrtf(tmax + 1e-3f);
    const int blo = binOf(qmn - r);
    const int bhi = binOf(qmx + r);
    const int* __restrict__ pb = pbase + b * NB;
    const int* __restrict__ pc = pcnt + b * NB;
    const int jlo = pb[blo];
    const int jhi = pb[bhi] + pc[bhi];
    const long long len = jhi - jlo;
    const int s0 = jlo + (int)((len * g) / NSEG);
    const int s1 = jlo + (int)((len * (g + 1)) / NSEG);

    const float4* __restrict__ P = spk + (size_t)b * N;
    const int* __restrict__ I = ssidx + (size_t)b * N;

    float d0 = DINF, d1 = DINF, d2 = DINF;
    int   i0 = ISENT, i1 = ISENT, i2 = ISENT;

    for (int j0 = s0; j0 < s1; j0 += 256) {
        const int m = min(256, s1 - j0);
        if (tid < m) { s_p[tid] = P[j0 + tid]; s_i[tid] = I[j0 + tid]; }
        __syncthreads();
        for (int k = 0; k < m; ++k) {
            float4 p = s_p[k];
            float dot2 = (qx * p.x + qy * p.y) + qz * p.z;   // == 2*dot, exact
            float dd   = (qs_ + p.w) - dot2;
            if (__builtin_expect(dd <= tq, 0))
                ins_lex(d0, d1, d2, i0, i1, i2, dd, s_i[k]);
        }
        __syncthreads();
    }

    const size_t off = (size_t)g * BS + gq;
    pd0[off] = d0; pd1[off] = d1; pd2[off] = d2;
    pi0[off] = i0; pi1[off] = i1; pi2[off] = i2;
}

__global__ __launch_bounds__(256)
void knn3_bmerge(const float* __restrict__ pd0, const float* __restrict__ pd1,
                 const float* __restrict__ pd2,
                 const int* __restrict__ pi0, const int* __restrict__ pi1,
                 const int* __restrict__ pi2,
                 const int* __restrict__ sqid, int BS,
                 int* __restrict__ idx0, int* __restrict__ idx1,
                 int* __restrict__ idx2,
                 float* __restrict__ w0, float* __restrict__ w1,
                 float* __restrict__ w2)
{
#pragma clang fp contract(off)
    const int gq = blockIdx.x * 256 + threadIdx.x;
    if (gq >= BS) return;
    float d0 = DINF, d1 = DINF, d2 = DINF;
    int   i0 = ISENT, i1 = ISENT, i2 = ISENT;
    for (int c = 0; c < NSEG; ++c) {
        const size_t off = (size_t)c * BS + gq;
        ins_lex_nb(d0, d1, d2, i0, i1, i2, pd0[off], pi0[off]);
        ins_lex_nb(d0, d1, d2, i0, i1, i2, pd1[off], pi1[off]);
        ins_lex_nb(d0, d1, d2, i0, i1, i2, pd2[off], pi2[off]);
    }
    const float r0 = 1.0f / (d0 + 1e-8f);
    const float r1 = 1.0f / (d1 + 1e-8f);
    const float r2 = 1.0f / (d2 + 1e-8f);
    const float sum = (r0 + r1) + r2;             // np sum order
    const int oq = sqid[gq];
    idx0[oq] = i0; idx1[oq] = i1; idx2[oq] = i2;
    w0[oq] = r0 / sum; w1[oq] = r1 / sum; w2[oq] = r2 / sum;
}

__global__ __launch_bounds__(256)
void interp_kernel(const float* __restrict__ points1,
                   const int* __restrict__ idx0, const int* __restrict__ idx1,
                   const int* __restrict__ idx2,
                   const float* __restrict__ w0, const float* __restrict__ w1,
                   const float* __restrict__ w2,
                   float* __restrict__ out, int N, int S, int D)
{
#pragma clang fp contract(off)
    __shared__ float row[8192];
    const int bd = blockIdx.x;
    const int b  = bd / D;
    const float* __restrict__ src = points1 + (size_t)bd * N;

    for (int i = threadIdx.x * 4; i < N; i += blockDim.x * 4) {
        *reinterpret_cast<float4*>(&row[i]) =
            *reinterpret_cast<const float4*>(src + i);
    }
    __syncthreads();

    float* __restrict__ dst = out + (size_t)bd * S;
    const int qb = b * S;
    for (int s = threadIdx.x; s < S; s += blockDim.x) {
        int q = qb + s;
        float a = row[idx0[q]] * w0[q];
        float c = row[idx1[q]] * w1[q];
        float e = row[idx2[q]] * w2[q];
        dst[s] = (a + c) + e;                     // np sum order
    }
}

extern "C" void kernel_launch(void* const* d_in, const int* in_sizes, int n_in,
                              void* d_out, int out_size, void* d_ws, size_t ws_size,
                              hipStream_t stream) {
    const float* xyz1    = (const float*)d_in[0];
    const float* xyz2    = (const float*)d_in[1];
    const float* points1 = (const float*)d_in[2];
    float* out = (float*)d_out;

    const int B = 8;
    const int N = in_sizes[0] / (3 * B);
    const int S = in_sizes[1] / (3 * B);
    const int D = in_sizes[2] / (B * N);
    const int BS = B * S;
    const int BN = B * N;

    // ws layout (float4 first for alignment)
    float4* spk  = (float4*)d_ws;                       // BN
    float*  pd0  = (float*)(spk + (size_t)BN);          // NSEG*BS each
    float*  pd1  = pd0 + (size_t)NSEG * BS;
    float*  pd2  = pd1 + (size_t)NSEG * BS;
    int*    pi0  = (int*)(pd2 + (size_t)NSEG * BS);
    int*    pi1  = pi0 + (size_t)NSEG * BS;
    int*    pi2  = pi1 + (size_t)NSEG * BS;
    int*    ssidx = pi2 + (size_t)NSEG * BS;            // BN
    int*    idx0 = ssidx + (size_t)BN;                  // BS each
    int*    idx1 = idx0 + BS;
    int*    idx2 = idx1 + BS;
    float*  w0   = (float*)(idx2 + BS);
    float*  w1   = w0 + BS;
    float*  w2   = w1 + BS;
    float*  tau  = w2 + BS;
    float*  sqx  = tau + BS;
    float*  sqy  = sqx + BS;
    float*  sqz  = sqy + BS;
    float*  sqs  = sqz + BS;
    float*  stau = sqs + BS;
    int*    sqid = (int*)(stau + BS);
    int*    pcnt = sqid + BS;                           // B*NB each
    int*    qcnt = pcnt + B * NB;
    int*    pbase = qcnt + B * NB;
    int*    qbase = pbase + B * NB;
    int*    pcur = qbase + B * NB;
    int*    qcur = pcur + B * NB;

    // tau sub-partials alias band partial slots 0..15 (dead before knn3_band)
    float* sd0 = pd0; float* sd1 = pd1; float* sd2 = pd2;

    hipMemsetAsync(pcnt, 0, (size_t)2 * B * NB * sizeof(int), stream);

    const int tot = BN + BS;
    bins_count<<<(tot + 255) / 256, 256, 0, stream>>>(xyz1, xyz2, B, N, S,
                                                      pcnt, qcnt);
    bins_scan<<<B, NB, 0, stream>>>(pcnt, qcnt, pbase, pcur, qbase, qcur);

    dim3 gt(BS / QT, NSUB);
    knn3_tau<<<gt, QT, 0, stream>>>(xyz1, xyz2, B, N, S, BS, sd0, sd1, sd2);
    tau3_merge<<<(BS + 255) / 256, 256, 0, stream>>>(sd0, sd1, sd2, BS, tau);

    scatter_all<<<(tot + 255) / 256, 256, 0, stream>>>(xyz1, xyz2, tau,
                                                       pcur, qcur,
                                                       spk, ssidx,
                                                       sqx, sqy, sqz, sqs,
                                                       stau, sqid, B, N, S);

    dim3 gb(BS / 256, NSEG);                  // 64 x 16 = 1024 blocks
    knn3_band<<<gb, 256, 0, stream>>>(spk, ssidx, sqx, sqy, sqz, sqs, stau,
                                      pbase, pcnt, B, N, S, BS,
                                      pd0, pd1, pd2, pi0, pi1, pi2);

    knn3_bmerge<<<(BS + 255) / 256, 256, 0, stream>>>(pd0, pd1, pd2,
                                                      pi0, pi1, pi2,
                                                      sqid, BS,
                                                      idx0, idx1, idx2,
                                                      w0, w1, w2);

    interp_kernel<<<B * D, 256, 0, stream>>>(points1, idx0, idx1, idx2,
                                             w0, w1, w2, out, N, S, D);
}

// Round 15
// 111.246 us; speedup vs baseline: 1.6669x; 1.6669x over previous
//
#include <hip/hip_runtime.h>

// PointNet 3-NN feature interpolation, v15: scalar-pipe point stream.
// pack_points: xyz1 -> packed {2x,2y,2z,norm} float4 (1 MB/batch, L2).
// knn3_tau   : pts 0..1023 in 16 sub-chunks; BLOCK-UNIFORM point address ->
//              s_load (scalar cache); value-only top-3 -> sub-partials.
// tau3_merge : tau[q] = 3rd-smallest over first 1024 pts.
// knn3_main  : 16 chunks of 512; block-uniform s_load point stream; filter
//              d<=tau -> rare masked insert; partial slots 0..15. No LDS.
// knn3_merge : merge 16 partial top-3s (ascending slots), weights.
// interp     : per-(b,d) row staged in LDS, gather+weighted-sum.

constexpr int QT     = 256;   // threads per block (1 query each)
constexpr int TCS    = 64;    // tau sub-chunk points
constexpr int TSUB   = 16;    // tau sub-chunks (1024 pts)
constexpr int MCS    = 512;   // main chunk points
constexpr int NCHUNK = 16;    // main chunks
constexpr float DINF = 3.4e38f;

__device__ __forceinline__ void insert3b(float& d0, float& d1, float& d2,
                                         int& i0, int& i1, int& i2,
                                         float d, int n) {
    bool c0 = d < d0, c1 = d < d1, c2 = d < d2;
    float nd2 = c1 ? d1 : (c2 ? d : d2);
    int   ni2 = c1 ? i1 : (c2 ? n : i2);
    float nd1 = c0 ? d0 : (c1 ? d : d1);
    int   ni1 = c0 ? i0 : (c1 ? n : i1);
    float nd0 = c0 ? d  : d0;
    int   ni0 = c0 ? n  : i0;
    d0 = nd0; d1 = nd1; d2 = nd2;
    i0 = ni0; i1 = ni1; i2 = ni2;
}

__device__ __forceinline__ void ins_v(float& d0, float& d1, float& d2, float d) {
    bool c0 = d < d0, c1 = d < d1, c2 = d < d2;
    float n2 = c1 ? d1 : (c2 ? d : d2);
    float n1 = c0 ? d0 : (c1 ? d : d1);
    d0 = c0 ? d : d0; d1 = n1; d2 = n2;
}

// pk[b*N+n] = {2x, 2y, 2z, (x*x + y*y) + z*z}. 2x exact (pow2 scale);
// (qx*2x + qy*2y) + qz*2z rounds bit-identically to 2*((qx*x+qy*y)+qz*z);
// norm in np sum order. Identical to v4/v13 (both passed, absmax 0.015625).
__global__ __launch_bounds__(256)
void pack_points(const float* __restrict__ xyz1, float4* __restrict__ pk,
                 int B, int N)
{
#pragma clang fp contract(off)
    int t = blockIdx.x * 256 + threadIdx.x;
    if (t >= B * N) return;
    int b = t / N, n = t - b * N;
    const float* __restrict__ bx = xyz1 + (size_t)b * 3 * N;
    float x = bx[n], y = bx[N + n], z = bx[2 * N + n];
    pk[t] = make_float4(x + x, y + y, z + z, (x * x + y * y) + z * z);
}

// grid (BS/QT, TSUB). b, chunk base derived ONLY from blockIdx -> the point
// pointer is provably wave-uniform -> s_load via scalar cache (no LDS).
__global__ __launch_bounds__(256)
void knn3_tau(const float4* __restrict__ pk, const float* __restrict__ xyz2,
              int B, int N, int S, int BS,
              float* __restrict__ sd0, float* __restrict__ sd1,
              float* __restrict__ sd2)
{
#pragma clang fp contract(off)
    const int tile = blockIdx.x;
    const int tpb  = S / QT;                  // tiles per batch (8)
    const int b    = tile / tpb;              // block-uniform
    const int c    = blockIdx.y;              // block-uniform
    const int s    = (tile - b * tpb) * QT + threadIdx.x;
    const int q    = b * S + s;

    const float* __restrict__ q2p = xyz2 + (size_t)b * 3 * S;
    const float qx = q2p[s];
    const float qy = q2p[S + s];
    const float qz = q2p[2 * S + s];
    const float qss = (qx * qx + qy * qy) + qz * qz;

    const float4* __restrict__ pc = pk + (size_t)b * N + c * TCS;  // uniform

    float d0 = DINF, d1 = DINF, d2 = DINF;
#pragma unroll 16
    for (int k = 0; k < TCS; ++k) {
        float4 p = pc[k];                     // uniform addr -> s_load_dwordx4
        float dot2 = (qx * p.x + qy * p.y) + qz * p.z;   // == 2*dot, exact
        float d    = (qss + p.w) - dot2;
        ins_v(d0, d1, d2, d);
    }
    const size_t off = (size_t)c * BS + q;
    sd0[off] = d0; sd1[off] = d1; sd2[off] = d2;
}

__global__ __launch_bounds__(256)
void tau3_merge(const float* __restrict__ sd0, const float* __restrict__ sd1,
                const float* __restrict__ sd2, int BS,
                float* __restrict__ tau)
{
    const int q = blockIdx.x * 256 + threadIdx.x;
    if (q >= BS) return;
    float d0 = DINF, d1 = DINF, d2 = DINF;
#pragma unroll
    for (int c = 0; c < TSUB; ++c) {
        const size_t off = (size_t)c * BS + q;
        ins_v(d0, d1, d2, sd0[off]);
        ins_v(d0, d1, d2, sd1[off]);
        ins_v(d0, d1, d2, sd2[off]);
    }
    tau[q] = d2;
}

// grid (BS/QT, NCHUNK). Same uniform-pointer scheme; filter d<=tau.
__global__ __launch_bounds__(256)
void knn3_main(const float4* __restrict__ pk, const float* __restrict__ xyz2,
               const float* __restrict__ tau,
               int B, int N, int S, int BS,
               float* __restrict__ pd0, float* __restrict__ pd1,
               float* __restrict__ pd2,
               int* __restrict__ pi0, int* __restrict__ pi1,
               int* __restrict__ pi2)
{
#pragma clang fp contract(off)
    const int tile = blockIdx.x;
    const int tpb  = S / QT;                  // 8
    const int b    = tile / tpb;              // block-uniform
    const int c    = blockIdx.y;              // block-uniform
    const int s    = (tile - b * tpb) * QT + threadIdx.x;
    const int q    = b * S + s;
    const int n0   = c * MCS;

    const float* __restrict__ q2p = xyz2 + (size_t)b * 3 * S;
    const float qx = q2p[s];
    const float qy = q2p[S + s];
    const float qz = q2p[2 * S + s];
    const float qss = (qx * qx + qy * qy) + qz * qz;
    const float t0  = tau[q];

    const float4* __restrict__ pc = pk + (size_t)b * N + n0;  // uniform

    float d0 = DINF, d1 = DINF, d2 = DINF;
    int   i0 = 0, i1 = 0, i2 = 0;

#pragma unroll 16
    for (int k = 0; k < MCS; ++k) {
        float4 p = pc[k];                     // uniform addr -> s_load_dwordx4
        float dot2 = (qx * p.x + qy * p.y) + qz * p.z;   // == 2*dot, exact
        float d    = (qss + p.w) - dot2;
        if (__builtin_expect(d <= t0, 0))     // tau >= global d2: exact filter
            insert3b(d0, d1, d2, i0, i1, i2, d, n0 + k);
    }
    const size_t off = (size_t)c * BS + q;
    pd0[off] = d0; pd1[off] = d1; pd2[off] = d2;
    pi0[off] = i0; pi1[off] = i1; pi2[off] = i2;
}

__global__ __launch_bounds__(256)
void knn3_merge(const float* __restrict__ pd0, const float* __restrict__ pd1,
                const float* __restrict__ pd2,
                const int* __restrict__ pi0, const int* __restrict__ pi1,
                const int* __restrict__ pi2,
                int BS,
                int* __restrict__ idx0, int* __restrict__ idx1, int* __restrict__ idx2,
                float* __restrict__ w0, float* __restrict__ w1, float* __restrict__ w2)
{
#pragma clang fp contract(off)
    const int q = blockIdx.x * 256 + threadIdx.x;
    if (q >= BS) return;
    float d0 = DINF, d1 = DINF, d2 = DINF;
    int   i0 = 0, i1 = 0, i2 = 0;
    // ascending point-range order + strict-< == top_k lowest-index ties
    for (int c = 0; c < NCHUNK; ++c) {
        const size_t off = (size_t)c * BS + q;
        insert3b(d0, d1, d2, i0, i1, i2, pd0[off], pi0[off]);
        insert3b(d0, d1, d2, i0, i1, i2, pd1[off], pi1[off]);
        insert3b(d0, d1, d2, i0, i1, i2, pd2[off], pi2[off]);
    }
    const float r0 = 1.0f / (d0 + 1e-8f);
    const float r1 = 1.0f / (d1 + 1e-8f);
    const float r2 = 1.0f / (d2 + 1e-8f);
    const float sum = (r0 + r1) + r2;            // np sum order
    idx0[q] = i0; idx1[q] = i1; idx2[q] = i2;
    w0[q] = r0 / sum; w1[q] = r1 / sum; w2[q] = r2 / sum;
}

__global__ __launch_bounds__(256)
void interp_kernel(const float* __restrict__ points1,
                   const int* __restrict__ idx0, const int* __restrict__ idx1,
                   const int* __restrict__ idx2,
                   const float* __restrict__ w0, const float* __restrict__ w1,
                   const float* __restrict__ w2,
                   float* __restrict__ out, int N, int S, int D)
{
#pragma clang fp contract(off)
    __shared__ float row[8192];
    const int bd = blockIdx.x;
    const int b  = bd / D;
    const float* __restrict__ src = points1 + (size_t)bd * N;

    for (int i = threadIdx.x * 4; i < N; i += blockDim.x * 4) {
        *reinterpret_cast<float4*>(&row[i]) =
            *reinterpret_cast<const float4*>(src + i);
    }
    __syncthreads();

    float* __restrict__ dst = out + (size_t)bd * S;
    const int qb = b * S;
    for (int s = threadIdx.x; s < S; s += blockDim.x) {
        int q = qb + s;
        float a = row[idx0[q]] * w0[q];
        float c = row[idx1[q]] * w1[q];
        float e = row[idx2[q]] * w2[q];
        dst[s] = (a + c) + e;             // np sum order
    }
}

extern "C" void kernel_launch(void* const* d_in, const int* in_sizes, int n_in,
                              void* d_out, int out_size, void* d_ws, size_t ws_size,
                              hipStream_t stream) {
    const float* xyz1    = (const float*)d_in[0];
    const float* xyz2    = (const float*)d_in[1];
    const float* points1 = (const float*)d_in[2];
    float* out = (float*)d_out;

    const int B = 8;
    const int N = in_sizes[0] / (3 * B);
    const int S = in_sizes[1] / (3 * B);
    const int D = in_sizes[2] / (B * N);
    const int BS = B * S;
    const int BN = B * N;

    // ws: pk | pd0..2 | pi0..2 (NCHUNK*BS each) | idx/w/tau
    float4* pk  = (float4*)d_ws;
    float*  pd0 = (float*)(pk + (size_t)BN);
    float*  pd1 = pd0 + (size_t)NCHUNK * BS;
    float*  pd2 = pd1 + (size_t)NCHUNK * BS;
    int*    pi0 = (int*)(pd2 + (size_t)NCHUNK * BS);
    int*    pi1 = pi0 + (size_t)NCHUNK * BS;
    int*    pi2 = pi1 + (size_t)NCHUNK * BS;
    int*    idx0 = pi2 + (size_t)NCHUNK * BS;
    int*    idx1 = idx0 + BS;
    int*    idx2 = idx1 + BS;
    float*  w0   = (float*)(idx2 + BS);
    float*  w1   = w0 + BS;
    float*  w2   = w1 + BS;
    float*  tau  = w2 + BS;

    // tau sub-partials alias pd0..pd2 slots 0..15 (dead before knn3_main
    // writes them; same-stream ordering guarantees tau3_merge reads first).
    pack_points<<<(BN + 255) / 256, 256, 0, stream>>>(xyz1, pk, B, N);

    dim3 gt(BS / QT, TSUB);                   // 64 x 16 = 1024 blocks
    knn3_tau<<<gt, QT, 0, stream>>>(pk, xyz2, B, N, S, BS, pd0, pd1, pd2);

    tau3_merge<<<(BS + 255) / 256, 256, 0, stream>>>(pd0, pd1, pd2, BS, tau);

    dim3 gm(BS / QT, NCHUNK);                 // 64 x 16 = 1024 blocks
    knn3_main<<<gm, QT, 0, stream>>>(pk, xyz2, tau, B, N, S, BS,
                                     pd0, pd1, pd2, pi0, pi1, pi2);

    knn3_merge<<<(BS + 255) / 256, 256, 0, stream>>>(pd0, pd1, pd2, pi0, pi1, pi2,
                                                     BS,
                                                     idx0, idx1, idx2, w0, w1, w2);

    interp_kernel<<<B * D, 256, 0, stream>>>(points1, idx0, idx1, idx2,
                                             w0, w1, w2, out, N, S, D);
}

// Round 16
// 107.623 us; speedup vs baseline: 1.7230x; 1.0337x over previous
//
#include <hip/hip_runtime.h>

// PointNet 3-NN feature interpolation, v16: monolithic wave-KNN.
// knn3_mono: block = 4 waves x 4 queries = 16 queries. Loop over 16 chunks of
//            512 pts: stage {2x,2y,2z,norm} to LDS (v9-proven), lanes partition
//            the chunk (vector ds_read: one instr = 64 points), lex (d,idx)
//            running top-3 per lane. Chunks 0-1 unconditional; then in-register
//            tau (3rd-smallest of first 1024, value butterfly); chunks 2-15
//            filtered d<=tau. Final lex butterfly -> weights inline.
// interp   : per-(b,d) row staged in LDS, gather+weighted-sum.

constexpr int QT  = 256;     // threads per block
constexpr int CS  = 512;     // points per chunk
constexpr int NCH = 16;      // chunks (N = 8192)
constexpr int QW  = 4;       // queries per wave
constexpr int QPB = 16;      // queries per block (4 waves x QW)
constexpr float DINF = 3.4e38f;
constexpr int   ISENT = 0x7fffffff;

// guarded lexicographic (d, idx) insert — order-independent exact top-3
__device__ __forceinline__ void ins_lex(float& d0, float& d1, float& d2,
                                        int& i0, int& i1, int& i2,
                                        float d, int n) {
    bool l2 = (d < d2) || (d == d2 && n < i2);
    if (l2) {
        bool l1 = (d < d1) || (d == d1 && n < i1);
        bool l0 = (d < d0) || (d == d0 && n < i0);
        d2 = l1 ? d1 : d;  i2 = l1 ? i1 : n;
        d1 = l0 ? d0 : (l1 ? d : d1);
        i1 = l0 ? i0 : (l1 ? n : i1);
        d0 = l0 ? d  : d0; i0 = l0 ? n : i0;
    }
}

// branchless lexicographic insert (butterfly merge)
__device__ __forceinline__ void ins_lex_nb(float& d0, float& d1, float& d2,
                                           int& i0, int& i1, int& i2,
                                           float d, int n) {
    bool l2 = (d < d2) || (d == d2 && n < i2);
    bool l1 = (d < d1) || (d == d1 && n < i1);
    bool l0 = (d < d0) || (d == d0 && n < i0);
    float nd2 = l1 ? d1 : (l2 ? d : d2);
    int   ni2 = l1 ? i1 : (l2 ? n : i2);
    float nd1 = l0 ? d0 : (l1 ? d : d1);
    int   ni1 = l0 ? i0 : (l1 ? n : i1);
    d0 = l0 ? d : d0;  i0 = l0 ? n : i0;
    d1 = nd1; d2 = nd2; i1 = ni1; i2 = ni2;
}

// value-only top-3 insert (tau butterfly)
__device__ __forceinline__ void ins_v(float& d0, float& d1, float& d2, float d) {
    bool c0 = d < d0, c1 = d < d1, c2 = d < d2;
    float n2 = c1 ? d1 : (c2 ? d : d2);
    float n1 = c0 ? d0 : (c1 ? d : d1);
    d0 = c0 ? d : d0; d1 = n1; d2 = n2;
}

// Stage CS pts as {2x,2y,2z,norm}: 2x exact (pow2); (qx*2x+qy*2y)+qz*2z rounds
// bit-identically to 2*((qx*x+qy*y)+qz*z); norm in np sum order. (v9-proven)
__device__ __forceinline__ void stage_chunk(float4* spt,
                                            const float* __restrict__ bx,
                                            int N, int tid) {
#pragma clang fp contract(off)
    const float* __restrict__ by = bx + N;
    const float* __restrict__ bz = by + N;
    for (int i = tid * 4; i < CS; i += QT * 4) {
        float4 vx = *reinterpret_cast<const float4*>(bx + i);
        float4 vy = *reinterpret_cast<const float4*>(by + i);
        float4 vz = *reinterpret_cast<const float4*>(bz + i);
        spt[i + 0] = make_float4(vx.x + vx.x, vy.x + vy.x, vz.x + vz.x,
                                 (vx.x*vx.x + vy.x*vy.x) + vz.x*vz.x);
        spt[i + 1] = make_float4(vx.y + vx.y, vy.y + vy.y, vz.y + vz.y,
                                 (vx.y*vx.y + vy.y*vy.y) + vz.y*vz.y);
        spt[i + 2] = make_float4(vx.z + vx.z, vy.z + vy.z, vz.z + vz.z,
                                 (vx.z*vx.z + vy.z*vy.z) + vz.z*vz.z);
        spt[i + 3] = make_float4(vx.w + vx.w, vy.w + vy.w, vz.w + vz.w,
                                 (vx.w*vx.w + vy.w*vy.w) + vz.w*vz.w);
    }
}

__global__ __launch_bounds__(256)
void knn3_mono(const float* __restrict__ xyz1, const float* __restrict__ xyz2,
               int B, int N, int S,
               int* __restrict__ idx0, int* __restrict__ idx1,
               int* __restrict__ idx2,
               float* __restrict__ w0, float* __restrict__ w1,
               float* __restrict__ w2)
{
#pragma clang fp contract(off)
    __shared__ float4 spt[CS];
    const int tid  = threadIdx.x;
    const int lane = tid & 63;
    const int wav  = tid >> 6;                 // 0..3
    const int tile = blockIdx.x;               // S/QPB tiles per batch
    const int tpb  = S / QPB;                  // 128
    const int b    = tile / tpb;               // block-uniform
    const int s0   = (tile - b * tpb) * QPB + wav * QW;  // wave's 1st query

    const float* __restrict__ q2p = xyz2 + (size_t)b * 3 * S;
    float qx[QW], qy[QW], qz[QW], qs[QW];
#pragma unroll
    for (int j = 0; j < QW; ++j) {             // uniform addr -> broadcast
        qx[j] = q2p[s0 + j];
        qy[j] = q2p[S + s0 + j];
        qz[j] = q2p[2 * S + s0 + j];
        qs[j] = (qx[j] * qx[j] + qy[j] * qy[j]) + qz[j] * qz[j];
    }

    float d0[QW], d1[QW], d2[QW];
    int   i0[QW], i1[QW], i2[QW];
#pragma unroll
    for (int j = 0; j < QW; ++j) {
        d0[j] = d1[j] = d2[j] = DINF;
        i0[j] = i1[j] = i2[j] = ISENT;
    }
    float tt[QW];
#pragma unroll
    for (int j = 0; j < QW; ++j) tt[j] = DINF;

    const float* __restrict__ bx = xyz1 + (size_t)b * 3 * N;

    for (int c = 0; c < NCH; ++c) {
        stage_chunk(spt, bx + c * CS, N, tid);
        __syncthreads();

        if (c < 2) {
            // phase A: no filter (guard inside ins_lex; mostly taken early)
#pragma unroll
            for (int i = 0; i < CS / 64; ++i) {
                float4 p = spt[lane + 64 * i];          // vector ds_read
                const int n = c * CS + lane + 64 * i;   // lane-seq ascending
#pragma unroll
                for (int j = 0; j < QW; ++j) {
                    float dot2 = (qx[j] * p.x + qy[j] * p.y) + qz[j] * p.z;
                    float d    = (qs[j] + p.w) - dot2;  // exact == ref rounding
                    ins_lex(d0[j], d1[j], d2[j], i0[j], i1[j], i2[j], d, n);
                }
            }
        } else {
            // phase B: tau-filtered (tau >= global d2 -> exact)
#pragma unroll
            for (int i = 0; i < CS / 64; ++i) {
                float4 p = spt[lane + 64 * i];
                const int n = c * CS + lane + 64 * i;
#pragma unroll
                for (int j = 0; j < QW; ++j) {
                    float dot2 = (qx[j] * p.x + qy[j] * p.y) + qz[j] * p.z;
                    float d    = (qs[j] + p.w) - dot2;
                    if (__builtin_expect(d <= tt[j], 0))
                        ins_lex(d0[j], d1[j], d2[j], i0[j], i1[j], i2[j], d, n);
                }
            }
        }
        __syncthreads();

        if (c == 1) {
            // in-register tau: 3rd-smallest VALUE over first 1024 pts
#pragma unroll
            for (int j = 0; j < QW; ++j) {
                float t0 = d0[j], t1 = d1[j], t2 = d2[j];
#pragma unroll
                for (int m = 32; m >= 1; m >>= 1) {
                    float a0 = __shfl_xor(t0, m);
                    float a1 = __shfl_xor(t1, m);
                    float a2 = __shfl_xor(t2, m);
                    ins_v(t0, t1, t2, a0);
                    ins_v(t0, t1, t2, a1);
                    ins_v(t0, t1, t2, a2);
                }
                tt[j] = t2;
            }
        }
    }

    // final lex butterfly: exact top-3, order-independent ties
#pragma unroll
    for (int m = 32; m >= 1; m >>= 1) {
#pragma unroll
        for (int j = 0; j < QW; ++j) {
            float a0 = __shfl_xor(d0[j], m);
            float a1 = __shfl_xor(d1[j], m);
            float a2 = __shfl_xor(d2[j], m);
            int   b0 = __shfl_xor(i0[j], m);
            int   b1 = __shfl_xor(i1[j], m);
            int   b2 = __shfl_xor(i2[j], m);
            ins_lex_nb(d0[j], d1[j], d2[j], i0[j], i1[j], i2[j], a0, b0);
            ins_lex_nb(d0[j], d1[j], d2[j], i0[j], i1[j], i2[j], a1, b1);
            ins_lex_nb(d0[j], d1[j], d2[j], i0[j], i1[j], i2[j], a2, b2);
        }
    }

#pragma unroll
    for (int j = 0; j < QW; ++j) {
        if (lane == j) {                        // static j
            const int q = b * S + s0 + j;
            float r0 = 1.0f / (d0[j] + 1e-8f);
            float r1 = 1.0f / (d1[j] + 1e-8f);
            float r2 = 1.0f / (d2[j] + 1e-8f);
            float sum = (r0 + r1) + r2;         // np sum order
            idx0[q] = i0[j]; idx1[q] = i1[j]; idx2[q] = i2[j];
            w0[q] = r0 / sum; w1[q] = r1 / sum; w2[q] = r2 / sum;
        }
    }
}

__global__ __launch_bounds__(256)
void interp_kernel(const float* __restrict__ points1,
                   const int* __restrict__ idx0, const int* __restrict__ idx1,
                   const int* __restrict__ idx2,
                   const float* __restrict__ w0, const float* __restrict__ w1,
                   const float* __restrict__ w2,
                   float* __restrict__ out, int N, int S, int D)
{
#pragma clang fp contract(off)
    __shared__ float row[8192];
    const int bd = blockIdx.x;
    const int b  = bd / D;
    const float* __restrict__ src = points1 + (size_t)bd * N;

    for (int i = threadIdx.x * 4; i < N; i += blockDim.x * 4) {
        *reinterpret_cast<float4*>(&row[i]) =
            *reinterpret_cast<const float4*>(src + i);
    }
    __syncthreads();

    float* __restrict__ dst = out + (size_t)bd * S;
    const int qb = b * S;
    for (int s = threadIdx.x; s < S; s += blockDim.x) {
        int q = qb + s;
        float a = row[idx0[q]] * w0[q];
        float c = row[idx1[q]] * w1[q];
        float e = row[idx2[q]] * w2[q];
        dst[s] = (a + c) + e;                   // np sum order
    }
}

extern "C" void kernel_launch(void* const* d_in, const int* in_sizes, int n_in,
                              void* d_out, int out_size, void* d_ws, size_t ws_size,
                              hipStream_t stream) {
    const float* xyz1    = (const float*)d_in[0];
    const float* xyz2    = (const float*)d_in[1];
    const float* points1 = (const float*)d_in[2];
    float* out = (float*)d_out;

    const int B = 8;
    const int N = in_sizes[0] / (3 * B);
    const int S = in_sizes[1] / (3 * B);
    const int D = in_sizes[2] / (B * N);
    const int BS = B * S;

    int*   idx0 = (int*)d_ws;
    int*   idx1 = idx0 + BS;
    int*   idx2 = idx1 + BS;
    float* w0   = (float*)(idx2 + BS);
    float* w1   = w0 + BS;
    float* w2   = w1 + BS;

    knn3_mono<<<BS / QPB, QT, 0, stream>>>(xyz1, xyz2, B, N, S,
                                           idx0, idx1, idx2, w0, w1, w2);

    interp_kernel<<<B * D, 256, 0, stream>>>(points1, idx0, idx1, idx2,
                                             w0, w1, w2, out, N, S, D);
}

// Round 17
// 101.766 us; speedup vs baseline: 1.8221x; 1.0575x over previous
//
#include <hip/hip_runtime.h>

// PointNet 3-NN feature interpolation, v17 = v16 + {XOR-swizzled LDS,
// packed staging + double buffer, cheap per-lane inserts}.
// pack_points: xyz1 -> packed {2x,2y,2z,norm} float4 (1 MB/batch, L2).
// knn3_mono  : block = 4 waves x 4 queries = 16 queries; 16 chunks of 512;
//              lanes partition the chunk (conflict-free swizzled ds_read);
//              chunks 0-1 unconditional insert3b, in-register tau (value
//              butterfly over first 1024 pts), chunks 2-15 filtered d<=tau;
//              final lex butterfly; weights inline.
// interp     : per-(b,d) row staged in LDS, gather+weighted-sum.

constexpr int QT  = 256;     // threads per block
constexpr int CS  = 512;     // points per chunk
constexpr int NCH = 16;      // chunks (N = 8192)
constexpr int QW  = 4;       // queries per wave
constexpr int QPB = 16;      // queries per block
constexpr float DINF = 3.4e38f;
constexpr int   ISENT = 0x7fffffff;

// strict-< top-3 insert (per-lane stream is ascending-n => lex-equivalent)
__device__ __forceinline__ void insert3b(float& d0, float& d1, float& d2,
                                         int& i0, int& i1, int& i2,
                                         float d, int n) {
    bool c0 = d < d0, c1 = d < d1, c2 = d < d2;
    float nd2 = c1 ? d1 : (c2 ? d : d2);
    int   ni2 = c1 ? i1 : (c2 ? n : i2);
    float nd1 = c0 ? d0 : (c1 ? d : d1);
    int   ni1 = c0 ? i0 : (c1 ? n : i1);
    float nd0 = c0 ? d  : d0;
    int   ni0 = c0 ? n  : i0;
    d0 = nd0; d1 = nd1; d2 = nd2;
    i0 = ni0; i1 = ni1; i2 = ni2;
}

// branchless lexicographic insert (cross-lane butterfly only)
__device__ __forceinline__ void ins_lex_nb(float& d0, float& d1, float& d2,
                                           int& i0, int& i1, int& i2,
                                           float d, int n) {
    bool l2 = (d < d2) || (d == d2 && n < i2);
    bool l1 = (d < d1) || (d == d1 && n < i1);
    bool l0 = (d < d0) || (d == d0 && n < i0);
    float nd2 = l1 ? d1 : (l2 ? d : d2);
    int   ni2 = l1 ? i1 : (l2 ? n : i2);
    float nd1 = l0 ? d0 : (l1 ? d : d1);
    int   ni1 = l0 ? i0 : (l1 ? n : i1);
    d0 = l0 ? d : d0;  i0 = l0 ? n : i0;
    d1 = nd1; d2 = nd2; i1 = ni1; i2 = ni2;
}

// value-only top-3 insert (tau butterfly)
__device__ __forceinline__ void ins_v(float& d0, float& d1, float& d2, float d) {
    bool c0 = d < d0, c1 = d < d1, c2 = d < d2;
    float n2 = c1 ? d1 : (c2 ? d : d2);
    float n1 = c0 ? d0 : (c1 ? d : d1);
    d0 = c0 ? d : d0; d1 = n1; d2 = n2;
}

// pk[b*N+n] = {2x, 2y, 2z, (x*x + y*y) + z*z}. 2x exact (pow2 scale);
// (qx*2x+qy*2y)+qz*2z rounds bit-identically to 2*((qx*x+qy*y)+qz*z);
// norm in np sum order. Identical to v4/v13 (passed, absmax 0.015625).
__global__ __launch_bounds__(256)
void pack_points(const float* __restrict__ xyz1, float4* __restrict__ pk,
                 int B, int N)
{
#pragma clang fp contract(off)
    int t = blockIdx.x * 256 + threadIdx.x;
    if (t >= B * N) return;
    int b = t / N, n = t - b * N;
    const float* __restrict__ bx = xyz1 + (size_t)b * 3 * N;
    float x = bx[n], y = bx[N + n], z = bx[2 * N + n];
    pk[t] = make_float4(x + x, y + y, z + z, (x * x + y * y) + z * z);
}

// swizzled store: logical L -> physical L ^ ((L>>3)&7)  (bank-spread)
__device__ __forceinline__ void stage_swz(float4* dst, const float4* src,
                                          int tid) {
    const int a  = (tid >> 3) & 7;
    const int L0 = tid;
    const int L1 = tid + 256;         // ((L1>>3)&7) == a
    dst[L0 ^ a] = src[L0];
    dst[L1 ^ a] = src[L1];
}

__global__ __launch_bounds__(256)
void knn3_mono(const float4* __restrict__ pk, const float* __restrict__ xyz2,
               int B, int N, int S,
               int* __restrict__ idx0, int* __restrict__ idx1,
               int* __restrict__ idx2,
               float* __restrict__ w0, float* __restrict__ w1,
               float* __restrict__ w2)
{
#pragma clang fp contract(off)
    __shared__ float4 spt[2][CS];
    const int tid   = threadIdx.x;
    const int lane  = tid & 63;
    const int wav   = tid >> 6;
    const int lbase = lane ^ ((lane >> 3) & 7);   // conflict-free read base
    const int tile  = blockIdx.x;
    const int tpb   = S / QPB;                    // 128
    const int b     = tile / tpb;                 // block-uniform
    const int s0    = (tile - b * tpb) * QPB + wav * QW;

    const float* __restrict__ q2p = xyz2 + (size_t)b * 3 * S;
    float qx[QW], qy[QW], qz[QW], qs[QW];
#pragma unroll
    for (int j = 0; j < QW; ++j) {
        qx[j] = q2p[s0 + j];
        qy[j] = q2p[S + s0 + j];
        qz[j] = q2p[2 * S + s0 + j];
        qs[j] = (qx[j] * qx[j] + qy[j] * qy[j]) + qz[j] * qz[j];
    }

    float d0[QW], d1[QW], d2[QW];
    int   i0[QW], i1[QW], i2[QW];
    float tt[QW];
#pragma unroll
    for (int j = 0; j < QW; ++j) {
        d0[j] = d1[j] = d2[j] = DINF;
        i0[j] = i1[j] = i2[j] = ISENT;
        tt[j] = DINF;
    }

    const float4* __restrict__ pb = pk + (size_t)b * N;

    stage_swz(spt[0], pb, tid);
    __syncthreads();

    for (int c = 0; c < NCH; ++c) {
        const int cur = c & 1;
        if (c + 1 < NCH)
            stage_swz(spt[cur ^ 1], pb + (c + 1) * CS, tid);

        const float4* __restrict__ cb = spt[cur];
        if (c < 2) {
#pragma unroll
            for (int ii = 0; ii < CS / 64; ++ii) {
                float4 p = cb[lbase + 64 * ii];
                const int n = c * CS + lane + 64 * ii;
#pragma unroll
                for (int j = 0; j < QW; ++j) {
                    float dot2 = (qx[j] * p.x + qy[j] * p.y) + qz[j] * p.z;
                    float d    = (qs[j] + p.w) - dot2;  // == ref rounding
                    insert3b(d0[j], d1[j], d2[j], i0[j], i1[j], i2[j], d, n);
                }
            }
        } else {
#pragma unroll
            for (int ii = 0; ii < CS / 64; ++ii) {
                float4 p = cb[lbase + 64 * ii];
                const int n = c * CS + lane + 64 * ii;
#pragma unroll
                for (int j = 0; j < QW; ++j) {
                    float dot2 = (qx[j] * p.x + qy[j] * p.y) + qz[j] * p.z;
                    float d    = (qs[j] + p.w) - dot2;
                    if (__builtin_expect(d <= tt[j], 0))  // tau>=global d2
                        insert3b(d0[j], d1[j], d2[j], i0[j], i1[j], i2[j], d, n);
                }
            }
        }
        __syncthreads();     // staging writes done; scan reads done

        if (c == 1) {
            // in-register tau: 3rd-smallest VALUE over first 1024 pts
#pragma unroll
            for (int j = 0; j < QW; ++j) {
                float t0 = d0[j], t1 = d1[j], t2 = d2[j];
#pragma unroll
                for (int m = 32; m >= 1; m >>= 1) {
                    float a0 = __shfl_xor(t0, m);
                    float a1 = __shfl_xor(t1, m);
                    float a2 = __shfl_xor(t2, m);
                    ins_v(t0, t1, t2, a0);
                    ins_v(t0, t1, t2, a1);
                    ins_v(t0, t1, t2, a2);
                }
                tt[j] = t2;
            }
        }
    }

    // final lex butterfly: exact top-3 with top_k lowest-index ties
#pragma unroll
    for (int m = 32; m >= 1; m >>= 1) {
#pragma unroll
        for (int j = 0; j < QW; ++j) {
            float a0 = __shfl_xor(d0[j], m);
            float a1 = __shfl_xor(d1[j], m);
            float a2 = __shfl_xor(d2[j], m);
            int   b0 = __shfl_xor(i0[j], m);
            int   b1 = __shfl_xor(i1[j], m);
            int   b2 = __shfl_xor(i2[j], m);
            ins_lex_nb(d0[j], d1[j], d2[j], i0[j], i1[j], i2[j], a0, b0);
            ins_lex_nb(d0[j], d1[j], d2[j], i0[j], i1[j], i2[j], a1, b1);
            ins_lex_nb(d0[j], d1[j], d2[j], i0[j], i1[j], i2[j], a2, b2);
        }
    }

#pragma unroll
    for (int j = 0; j < QW; ++j) {
        if (lane == j) {
            const int q = b * S + s0 + j;
            float r0 = 1.0f / (d0[j] + 1e-8f);
            float r1 = 1.0f / (d1[j] + 1e-8f);
            float r2 = 1.0f / (d2[j] + 1e-8f);
            float sum = (r0 + r1) + r2;         // np sum order
            idx0[q] = i0[j]; idx1[q] = i1[j]; idx2[q] = i2[j];
            w0[q] = r0 / sum; w1[q] = r1 / sum; w2[q] = r2 / sum;
        }
    }
}

__global__ __launch_bounds__(256)
void interp_kernel(const float* __restrict__ points1,
                   const int* __restrict__ idx0, const int* __restrict__ idx1,
                   const int* __restrict__ idx2,
                   const float* __restrict__ w0, const float* __restrict__ w1,
                   const float* __restrict__ w2,
                   float* __restrict__ out, int N, int S, int D)
{
#pragma clang fp contract(off)
    __shared__ float row[8192];
    const int bd = blockIdx.x;
    const int b  = bd / D;
    const float* __restrict__ src = points1 + (size_t)bd * N;

    for (int i = threadIdx.x * 4; i < N; i += blockDim.x * 4) {
        *reinterpret_cast<float4*>(&row[i]) =
            *reinterpret_cast<const float4*>(src + i);
    }
    __syncthreads();

    float* __restrict__ dst = out + (size_t)bd * S;
    const int qb = b * S;
    for (int s = threadIdx.x; s < S; s += blockDim.x) {
        int q = qb + s;
        float a = row[idx0[q]] * w0[q];
        float c = row[idx1[q]] * w1[q];
        float e = row[idx2[q]] * w2[q];
        dst[s] = (a + c) + e;                   // np sum order
    }
}

extern "C" void kernel_launch(void* const* d_in, const int* in_sizes, int n_in,
                              void* d_out, int out_size, void* d_ws, size_t ws_size,
                              hipStream_t stream) {
    const float* xyz1    = (const float*)d_in[0];
    const float* xyz2    = (const float*)d_in[1];
    const float* points1 = (const float*)d_in[2];
    float* out = (float*)d_out;

    const int B = 8;
    const int N = in_sizes[0] / (3 * B);
    const int S = in_sizes[1] / (3 * B);
    const int D = in_sizes[2] / (B * N);
    const int BS = B * S;
    const int BN = B * N;

    // ws: pk (16B aligned) | idx0..2 | w0..2
    float4* pk   = (float4*)d_ws;
    int*    idx0 = (int*)(pk + (size_t)BN);
    int*    idx1 = idx0 + BS;
    int*    idx2 = idx1 + BS;
    float*  w0   = (float*)(idx2 + BS);
    float*  w1   = w0 + BS;
    float*  w2   = w1 + BS;

    pack_points<<<(BN + 255) / 256, 256, 0, stream>>>(xyz1, pk, B, N);

    knn3_mono<<<BS / QPB, QT, 0, stream>>>(pk, xyz2, B, N, S,
                                           idx0, idx1, idx2, w0, w1, w2);

    interp_kernel<<<B * D, 256, 0, stream>>>(points1, idx0, idx1, idx2,
                                             w0, w1, w2, out, N, S, D);
}